// Round 1
// baseline (68.272 us; speedup 1.0000x reference)
//
#include <hip/hip_runtime.h>
#include <math.h>

#define B_ 32768
#define E_ 256
#define S_ 1024
#define EPS_COS 1e-8f
#define EPS_NORM 1e-12f
#define NB2 (B_ / 256)   // loss-kernel blocks = 128

// ---------------- kernel 1: zero the accumulators --------------------------
__global__ void zero_ws_kernel(float* s, float* cnt, int* flags) {
    int i = blockIdx.x * blockDim.x + threadIdx.x;
    if (i < S_) { s[i] = 0.f; cnt[i] = 0.f; }
    if (i < 2)  flags[i] = 0;   // npos, nneg
}

// ---------------- kernel 2: per-row sums + normalized output ---------------
// one 64-lane wave per row (E=256 -> float4 per lane), 4 waves / block
__global__ __launch_bounds__(256) void rows_kernel(
        const float* __restrict__ x, const int* __restrict__ tgt,
        float* __restrict__ outN,
        float* __restrict__ rowsum, float* __restrict__ sqsum,
        float* __restrict__ s, float* __restrict__ cnt) {
    int wave = threadIdx.x >> 6;
    int lane = threadIdx.x & 63;
    int row  = blockIdx.x * 4 + wave;

    const float4* xr = (const float4*)(x + (size_t)row * E_);
    float4 v = xr[lane];
    float sum = v.x + v.y + v.z + v.w;
    float sq  = v.x * v.x + v.y * v.y + v.z * v.z + v.w * v.w;
    // 64-lane butterfly: every lane ends with the full reductions
    #pragma unroll
    for (int o = 32; o >= 1; o >>= 1) {
        sum += __shfl_xor(sum, o, 64);
        sq  += __shfl_xor(sq,  o, 64);
    }
    float ne = sqrtf(sq);
    float rn = 1.0f / fmaxf(ne, EPS_NORM);
    float4 nv = make_float4(v.x * rn, v.y * rn, v.z * rn, v.w * rn);
    ((float4*)(outN + (size_t)row * E_))[lane] = nv;

    if (lane == 0) {
        rowsum[row] = sum;
        sqsum[row]  = sq;
        int t = tgt[row];
        atomicAdd(&s[t],  sum);
        atomicAdd(&cnt[t], 1.0f);
    }
}

// ---------------- kernel 3: c[k] = s/n, sign-bucket counts -----------------
__global__ void cvec_kernel(const float* __restrict__ s, const float* __restrict__ cnt,
                            float* __restrict__ c, int* __restrict__ flags) {
    int k = blockIdx.x * blockDim.x + threadIdx.x;
    if (k >= S_) return;
    float cv = s[k] / cnt[k];
    c[k] = cv;
    float nck = fabsf(cv) * 16.0f;          // sqrt(E)=sqrt(256)=16 exactly
    if (nck >= EPS_COS) {
        if (cv > 0.f) atomicAdd(&flags[0], 1);
        else          atomicAdd(&flags[1], 1);
    }
    // else: effectively-zero bucket (sim ~ b), counted as S - npos - nneg
}

// ---------------- kernel 4: per-row loss terms -----------------------------
__global__ __launch_bounds__(256) void loss_kernel(
        const float* __restrict__ rowsum, const float* __restrict__ sqsum,
        const int* __restrict__ tgt,
        const float* __restrict__ s, const float* __restrict__ cnt,
        const float* __restrict__ c, const int* __restrict__ flags,
        const float* __restrict__ wP, const float* __restrict__ bP,
        float* __restrict__ partials) {
    int i = blockIdx.x * blockDim.x + threadIdx.x;
    float w  = wP[0], b = bP[0];
    float wr = fmaxf(w, 0.f);
    int npos = flags[0], nneg = flags[1];

    float contrib = 0.f;
    if (i < B_) {
        int   t  = tgt[i];
        float rs = rowsum[i], sq = sqsum[i];
        float sj = s[t],      nj = cnt[t];

        float ne  = sqrtf(sq);
        float nem = fmaxf(ne, EPS_COS);

        // leave-one-out closed forms
        float dot = (sj * rs - sq) / nj;
        float nc  = sqrtf((float)E_ * sj * sj - 2.f * sj * rs + sq) / nj;
        float self_cos = dot / (nem * fmaxf(nc, EPS_COS));
        float self_sim = wr * self_cos + b;

        // other-speaker slots: value depends on k only via sign(c_k)
        float A  = wr * rs / (nem * 16.0f);
        float xp =  A + b, xm = -A + b, xz = b;

        // remove the target slot from its bucket
        float ct = c[t];
        int np = npos, nm = nneg, nz = S_ - npos - nneg;
        if (fabsf(ct) * 16.0f >= EPS_COS) { if (ct > 0.f) np--; else nm--; }
        else nz--;

        float m = self_sim;
        if (np > 0) m = fmaxf(m, xp);
        if (nm > 0) m = fmaxf(m, xm);
        if (nz > 0) m = fmaxf(m, xz);
        float ssum = expf(self_sim - m)
                   + (float)np * expf(xp - m)
                   + (float)nm * expf(xm - m)
                   + (float)nz * expf(xz - m);
        float lse = m + logf(ssum);
        contrib = lse - self_sim;
    }

    __shared__ float red[256];
    red[threadIdx.x] = contrib;
    __syncthreads();
    #pragma unroll
    for (int st = 128; st > 0; st >>= 1) {
        if (threadIdx.x < st) red[threadIdx.x] += red[threadIdx.x + st];
        __syncthreads();
    }
    if (threadIdx.x == 0) partials[blockIdx.x] = red[0];
}

// ---------------- kernel 5: final reduce -> loss ---------------------------
__global__ void final_kernel(const float* __restrict__ partials, float* __restrict__ out) {
    __shared__ float red[128];
    red[threadIdx.x] = partials[threadIdx.x];
    __syncthreads();
    #pragma unroll
    for (int st = 64; st > 0; st >>= 1) {
        if (threadIdx.x < st) red[threadIdx.x] += red[threadIdx.x + st];
        __syncthreads();
    }
    if (threadIdx.x == 0) out[0] = red[0];
}

extern "C" void kernel_launch(void* const* d_in, const int* in_sizes, int n_in,
                              void* d_out, int out_size, void* d_ws, size_t ws_size,
                              hipStream_t stream) {
    const float* inputs  = (const float*)d_in[0];
    const int*   targets = (const int*)d_in[1];
    const float* wP      = (const float*)d_in[2];
    const float* bP      = (const float*)d_in[3];
    float* outN = (float*)d_out;                    // [B,E] normalized
    float* outL = (float*)d_out + (size_t)B_ * E_;  // [1] loss

    // workspace layout (floats)
    float* wsf     = (float*)d_ws;
    float* rowsum  = wsf;                 // B
    float* sqsum   = wsf + B_;            // B
    float* sArr    = wsf + 2 * B_;        // S
    float* cntArr  = sArr + S_;           // S
    float* cArr    = cntArr + S_;         // S
    int*   flags   = (int*)(cArr + S_);   // 2 ints: npos, nneg
    float* partials = (float*)(flags + 2);// NB2

    zero_ws_kernel<<<(S_ + 255) / 256, 256, 0, stream>>>(sArr, cntArr, flags);
    rows_kernel<<<B_ / 4, 256, 0, stream>>>(inputs, targets, outN,
                                            rowsum, sqsum, sArr, cntArr);
    cvec_kernel<<<S_ / 256, 256, 0, stream>>>(sArr, cntArr, cArr, flags);
    loss_kernel<<<NB2, 256, 0, stream>>>(rowsum, sqsum, targets, sArr, cntArr,
                                         cArr, flags, wP, bP, partials);
    final_kernel<<<1, 128, 0, stream>>>(partials, outL);
}

// Round 3
// 48.054 us; speedup vs baseline: 1.4207x; 1.4207x over previous
//
#include <hip/hip_runtime.h>
#include <math.h>

#define B_ 32768
#define E_ 256
#define S_ 1024
#define EPS_COS 1e-8f
#define EPS_NORM 1e-12f

typedef float fx4 __attribute__((ext_vector_type(4)));

// ---------------- kernel 1: zero accumulators + loss slot ------------------
__global__ void zero_ws_kernel(float* s, float* cnt, float* outL) {
    int i = blockIdx.x * blockDim.x + threadIdx.x;
    if (i < S_) { s[i] = 0.f; cnt[i] = 0.f; }
    if (i == 0) outL[0] = 0.f;
}

// ---------------- kernel 2: per-row sums + normalized output ---------------
// 16 lanes per row, 4 rows per wave, 4 waves per block -> 16 rows/block.
__global__ __launch_bounds__(256) void rows_kernel(
        const float* __restrict__ x, const int* __restrict__ tgt,
        float* __restrict__ outN,
        float* __restrict__ rowsum, float* __restrict__ sqsum,
        float* __restrict__ s, float* __restrict__ cnt) {
    int wave = threadIdx.x >> 6;
    int lane = threadIdx.x & 63;
    int li   = lane & 15;          // lane within 16-group
    int sub  = lane >> 4;          // which row of the wave's 4
    int row  = blockIdx.x * 16 + wave * 4 + sub;

    const fx4* __restrict__ xr = (const fx4*)(x + (size_t)row * E_);
    fx4* __restrict__ orow = (fx4*)(outN + (size_t)row * E_);

    fx4 v0 = __builtin_nontemporal_load(&xr[li]);
    fx4 v1 = __builtin_nontemporal_load(&xr[li + 16]);
    fx4 v2 = __builtin_nontemporal_load(&xr[li + 32]);
    fx4 v3 = __builtin_nontemporal_load(&xr[li + 48]);

    float sum = (v0.x + v0.y + v0.z + v0.w) + (v1.x + v1.y + v1.z + v1.w)
              + (v2.x + v2.y + v2.z + v2.w) + (v3.x + v3.y + v3.z + v3.w);
    float sq  = (v0.x*v0.x + v0.y*v0.y + v0.z*v0.z + v0.w*v0.w)
              + (v1.x*v1.x + v1.y*v1.y + v1.z*v1.z + v1.w*v1.w)
              + (v2.x*v2.x + v2.y*v2.y + v2.z*v2.z + v2.w*v2.w)
              + (v3.x*v3.x + v3.y*v3.y + v3.z*v3.z + v3.w*v3.w);

    #pragma unroll
    for (int o = 8; o >= 1; o >>= 1) {   // stays within the 16-lane group
        sum += __shfl_xor(sum, o, 64);
        sq  += __shfl_xor(sq,  o, 64);
    }

    float ne = sqrtf(sq);
    float rn = 1.0f / fmaxf(ne, EPS_NORM);

    __builtin_nontemporal_store(v0 * rn, &orow[li]);
    __builtin_nontemporal_store(v1 * rn, &orow[li + 16]);
    __builtin_nontemporal_store(v2 * rn, &orow[li + 32]);
    __builtin_nontemporal_store(v3 * rn, &orow[li + 48]);

    if (li == 0) {                 // lanes 0,16,32,48: one row each
        rowsum[row] = sum;
        sqsum[row]  = sq;
        int t = tgt[row];
        atomicAdd(&s[t],  sum);
        atomicAdd(&cnt[t], 1.0f);
    }
}

// ---------------- kernel 3: fused c-buckets + per-row loss + reduce --------
__global__ __launch_bounds__(256) void loss_kernel(
        const float* __restrict__ rowsum, const float* __restrict__ sqsum,
        const int* __restrict__ tgt,
        const float* __restrict__ s, const float* __restrict__ cnt,
        const float* __restrict__ wP, const float* __restrict__ bP,
        float* __restrict__ outL) {
    // --- per-block recompute of sign-bucket counts over S (L2-hot, 8 KB) ---
    int packed = 0;   // (npos << 16) | nneg
    #pragma unroll
    for (int j = 0; j < S_ / 256; ++j) {
        int k = threadIdx.x * (S_ / 256) + j;
        float cv = s[k] / cnt[k];
        if (fabsf(cv) * 16.0f >= EPS_COS) packed += (cv > 0.f) ? (1 << 16) : 1;
    }
    __shared__ int ired[256];
    ired[threadIdx.x] = packed;
    __syncthreads();
    #pragma unroll
    for (int st = 128; st > 0; st >>= 1) {
        if (threadIdx.x < st) ired[threadIdx.x] += ired[threadIdx.x + st];
        __syncthreads();
    }
    int npos = ired[0] >> 16, nneg = ired[0] & 0xFFFF;

    // --- per-row loss ---
    int i = blockIdx.x * blockDim.x + threadIdx.x;   // grid = B/256 blocks
    float w  = wP[0], b = bP[0];
    float wr = fmaxf(w, 0.f);

    int   t  = tgt[i];
    float rs = rowsum[i], sq = sqsum[i];
    float sj = s[t],      nj = cnt[t];

    float ne  = sqrtf(sq);
    float nem = fmaxf(ne, EPS_COS);

    float dot = (sj * rs - sq) / nj;
    float nc  = sqrtf((float)E_ * sj * sj - 2.f * sj * rs + sq) / nj;
    float self_cos = dot / (nem * fmaxf(nc, EPS_COS));
    float self_sim = wr * self_cos + b;

    float A  = wr * rs / (nem * 16.0f);
    float xp =  A + b, xm = -A + b, xz = b;

    float ct = sj / nj;
    int np = npos, nm = nneg, nz = S_ - npos - nneg;
    if (fabsf(ct) * 16.0f >= EPS_COS) { if (ct > 0.f) np--; else nm--; }
    else nz--;

    float m = self_sim;
    if (np > 0) m = fmaxf(m, xp);
    if (nm > 0) m = fmaxf(m, xm);
    if (nz > 0) m = fmaxf(m, xz);
    float ssum = expf(self_sim - m)
               + (float)np * expf(xp - m)
               + (float)nm * expf(xm - m)
               + (float)nz * expf(xz - m);
    float contrib = m + logf(ssum) - self_sim;

    __shared__ float fred[256];
    fred[threadIdx.x] = contrib;
    __syncthreads();
    #pragma unroll
    for (int st = 128; st > 0; st >>= 1) {
        if (threadIdx.x < st) fred[threadIdx.x] += fred[threadIdx.x + st];
        __syncthreads();
    }
    if (threadIdx.x == 0) atomicAdd(outL, fred[0]);
}

extern "C" void kernel_launch(void* const* d_in, const int* in_sizes, int n_in,
                              void* d_out, int out_size, void* d_ws, size_t ws_size,
                              hipStream_t stream) {
    const float* inputs  = (const float*)d_in[0];
    const int*   targets = (const int*)d_in[1];
    const float* wP      = (const float*)d_in[2];
    const float* bP      = (const float*)d_in[3];
    float* outN = (float*)d_out;                    // [B,E] normalized
    float* outL = (float*)d_out + (size_t)B_ * E_;  // [1] loss

    float* wsf    = (float*)d_ws;
    float* rowsum = wsf;                 // B
    float* sqsum  = wsf + B_;            // B
    float* sArr   = wsf + 2 * B_;        // S
    float* cntArr = sArr + S_;           // S

    zero_ws_kernel<<<S_ / 256, 256, 0, stream>>>(sArr, cntArr, outL);
    rows_kernel<<<B_ / 16, 256, 0, stream>>>(inputs, targets, outN,
                                             rowsum, sqsum, sArr, cntArr);
    loss_kernel<<<B_ / 256, 256, 0, stream>>>(rowsum, sqsum, targets,
                                              sArr, cntArr, wP, bP, outL);
}

// Round 4
// 41.685 us; speedup vs baseline: 1.6378x; 1.1528x over previous
//
#include <hip/hip_runtime.h>
#include <math.h>

#define B_ 32768
#define E_ 256
#define S_ 1024
#define EPS_COS 1e-8f
#define EPS_NORM 1e-12f

typedef float fx4 __attribute__((ext_vector_type(4)));

// ---------------- kernel 1: zero accumulators + loss slot ------------------
__global__ void zero_ws_kernel(float* s, float* cnt, float* outL) {
    int i = blockIdx.x * blockDim.x + threadIdx.x;
    if (i < S_) { s[i] = 0.f; cnt[i] = 0.f; }
    if (i == 0) outL[0] = 0.f;
}

// ---------------- kernel 2: per-row sums + normalized output ---------------
// 16 lanes per row, 2 rows per group in one straight-line body (8 loads in
// flight, 4 independent reduce chains), 4 groups/wave, 4 waves/block.
// Block covers 32 rows; grid = B/32 = 1024 blocks (4 waves/SIMD resident).
__global__ __launch_bounds__(256) void rows_kernel(
        const float* __restrict__ x, const int* __restrict__ tgt,
        float* __restrict__ outN,
        float* __restrict__ rowsum, float* __restrict__ sqsum,
        float* __restrict__ s, float* __restrict__ cnt) {
    int wave = threadIdx.x >> 6;
    int lane = threadIdx.x & 63;
    int li   = lane & 15;          // lane within 16-group
    int sub  = lane >> 4;          // group within wave
    int rowA = blockIdx.x * 32 + wave * 8 + sub * 2;
    int rowB = rowA + 1;

    const fx4* __restrict__ xa = (const fx4*)(x + (size_t)rowA * E_);
    const fx4* __restrict__ xb = (const fx4*)(x + (size_t)rowB * E_);
    fx4* __restrict__ oa = (fx4*)(outN + (size_t)rowA * E_);
    fx4* __restrict__ ob = (fx4*)(outN + (size_t)rowB * E_);

    // 8 independent loads
    fx4 a0 = xa[li];
    fx4 a1 = xa[li + 16];
    fx4 a2 = xa[li + 32];
    fx4 a3 = xa[li + 48];
    fx4 b0 = xb[li];
    fx4 b1 = xb[li + 16];
    fx4 b2 = xb[li + 32];
    fx4 b3 = xb[li + 48];

    float sumA = (a0.x + a0.y + a0.z + a0.w) + (a1.x + a1.y + a1.z + a1.w)
               + (a2.x + a2.y + a2.z + a2.w) + (a3.x + a3.y + a3.z + a3.w);
    float sqA  = (a0.x*a0.x + a0.y*a0.y + a0.z*a0.z + a0.w*a0.w)
               + (a1.x*a1.x + a1.y*a1.y + a1.z*a1.z + a1.w*a1.w)
               + (a2.x*a2.x + a2.y*a2.y + a2.z*a2.z + a2.w*a2.w)
               + (a3.x*a3.x + a3.y*a3.y + a3.z*a3.z + a3.w*a3.w);
    float sumB = (b0.x + b0.y + b0.z + b0.w) + (b1.x + b1.y + b1.z + b1.w)
               + (b2.x + b2.y + b2.z + b2.w) + (b3.x + b3.y + b3.z + b3.w);
    float sqB  = (b0.x*b0.x + b0.y*b0.y + b0.z*b0.z + b0.w*b0.w)
               + (b1.x*b1.x + b1.y*b1.y + b1.z*b1.z + b1.w*b1.w)
               + (b2.x*b2.x + b2.y*b2.y + b2.z*b2.z + b2.w*b2.w)
               + (b3.x*b3.x + b3.y*b3.y + b3.z*b3.z + b3.w*b3.w);

    // 4 independent butterfly chains interleave (intra-16-lane)
    #pragma unroll
    for (int o = 8; o >= 1; o >>= 1) {
        sumA += __shfl_xor(sumA, o, 64);
        sqA  += __shfl_xor(sqA,  o, 64);
        sumB += __shfl_xor(sumB, o, 64);
        sqB  += __shfl_xor(sqB,  o, 64);
    }

    float rnA = 1.0f / fmaxf(sqrtf(sqA), EPS_NORM);
    float rnB = 1.0f / fmaxf(sqrtf(sqB), EPS_NORM);

    __builtin_nontemporal_store(a0 * rnA, &oa[li]);
    __builtin_nontemporal_store(a1 * rnA, &oa[li + 16]);
    __builtin_nontemporal_store(a2 * rnA, &oa[li + 32]);
    __builtin_nontemporal_store(a3 * rnA, &oa[li + 48]);
    __builtin_nontemporal_store(b0 * rnB, &ob[li]);
    __builtin_nontemporal_store(b1 * rnB, &ob[li + 16]);
    __builtin_nontemporal_store(b2 * rnB, &ob[li + 32]);
    __builtin_nontemporal_store(b3 * rnB, &ob[li + 48]);

    if (li == 0) {
        rowsum[rowA] = sumA;
        sqsum[rowA]  = sqA;
        rowsum[rowB] = sumB;
        sqsum[rowB]  = sqB;
        int tA = tgt[rowA], tB = tgt[rowB];
        atomicAdd(&s[tA],  sumA);
        atomicAdd(&cnt[tA], 1.0f);
        atomicAdd(&s[tB],  sumB);
        atomicAdd(&cnt[tB], 1.0f);
    }
}

// ---------------- kernel 3: fused c-buckets + per-row loss + reduce --------
__global__ __launch_bounds__(256) void loss_kernel(
        const float* __restrict__ rowsum, const float* __restrict__ sqsum,
        const int* __restrict__ tgt,
        const float* __restrict__ s, const float* __restrict__ cnt,
        const float* __restrict__ wP, const float* __restrict__ bP,
        float* __restrict__ outL) {
    // --- per-block recompute of sign-bucket counts over S (L2-hot, 8 KB) ---
    int packed = 0;   // (npos << 16) | nneg
    #pragma unroll
    for (int j = 0; j < S_ / 256; ++j) {
        int k = threadIdx.x * (S_ / 256) + j;
        float cv = s[k] / cnt[k];
        if (fabsf(cv) * 16.0f >= EPS_COS) packed += (cv > 0.f) ? (1 << 16) : 1;
    }
    __shared__ int ired[256];
    ired[threadIdx.x] = packed;
    __syncthreads();
    #pragma unroll
    for (int st = 128; st > 0; st >>= 1) {
        if (threadIdx.x < st) ired[threadIdx.x] += ired[threadIdx.x + st];
        __syncthreads();
    }
    int npos = ired[0] >> 16, nneg = ired[0] & 0xFFFF;

    // --- per-row loss ---
    int i = blockIdx.x * blockDim.x + threadIdx.x;   // grid = B/256 blocks
    float w  = wP[0], b = bP[0];
    float wr = fmaxf(w, 0.f);

    int   t  = tgt[i];
    float rs = rowsum[i], sq = sqsum[i];
    float sj = s[t],      nj = cnt[t];

    float ne  = sqrtf(sq);
    float nem = fmaxf(ne, EPS_COS);

    float dot = (sj * rs - sq) / nj;
    float nc  = sqrtf((float)E_ * sj * sj - 2.f * sj * rs + sq) / nj;
    float self_cos = dot / (nem * fmaxf(nc, EPS_COS));
    float self_sim = wr * self_cos + b;

    float A  = wr * rs / (nem * 16.0f);
    float xp =  A + b, xm = -A + b, xz = b;

    float ct = sj / nj;
    int np = npos, nm = nneg, nz = S_ - npos - nneg;
    if (fabsf(ct) * 16.0f >= EPS_COS) { if (ct > 0.f) np--; else nm--; }
    else nz--;

    float m = self_sim;
    if (np > 0) m = fmaxf(m, xp);
    if (nm > 0) m = fmaxf(m, xm);
    if (nz > 0) m = fmaxf(m, xz);
    float ssum = expf(self_sim - m)
               + (float)np * expf(xp - m)
               + (float)nm * expf(xm - m)
               + (float)nz * expf(xz - m);
    float contrib = m + logf(ssum) - self_sim;

    __shared__ float fred[256];
    fred[threadIdx.x] = contrib;
    __syncthreads();
    #pragma unroll
    for (int st = 128; st > 0; st >>= 1) {
        if (threadIdx.x < st) fred[threadIdx.x] += fred[threadIdx.x + st];
        __syncthreads();
    }
    if (threadIdx.x == 0) atomicAdd(outL, fred[0]);
}

extern "C" void kernel_launch(void* const* d_in, const int* in_sizes, int n_in,
                              void* d_out, int out_size, void* d_ws, size_t ws_size,
                              hipStream_t stream) {
    const float* inputs  = (const float*)d_in[0];
    const int*   targets = (const int*)d_in[1];
    const float* wP      = (const float*)d_in[2];
    const float* bP      = (const float*)d_in[3];
    float* outN = (float*)d_out;                    // [B,E] normalized
    float* outL = (float*)d_out + (size_t)B_ * E_;  // [1] loss

    float* wsf    = (float*)d_ws;
    float* rowsum = wsf;                 // B
    float* sqsum  = wsf + B_;            // B
    float* sArr   = wsf + 2 * B_;        // S
    float* cntArr = sArr + S_;           // S

    zero_ws_kernel<<<S_ / 256, 256, 0, stream>>>(sArr, cntArr, outL);
    rows_kernel<<<B_ / 32, 256, 0, stream>>>(inputs, targets, outN,
                                             rowsum, sqsum, sArr, cntArr);
    loss_kernel<<<B_ / 256, 256, 0, stream>>>(rowsum, sqsum, targets,
                                              sArr, cntArr, wP, bP, outL);
}

// Round 5
// 24.270 us; speedup vs baseline: 2.8131x; 1.7176x over previous
//
#include <hip/hip_runtime.h>
#include <math.h>

#define B_ 32768
#define E_ 256
#define S_ 1024
#define EPS_COS 1e-8f
#define EPS_NORM 1e-12f

typedef float fx4 __attribute__((ext_vector_type(4)));

// ---------------- kernel 1: zero accumulators + loss slot ------------------
__global__ void zero_ws_kernel(float* s, float* cnt, float* outL) {
    int i = blockIdx.x * blockDim.x + threadIdx.x;
    if (i < S_) { s[i] = 0.f; cnt[i] = 0.f; }
    if (i == 0) outL[0] = 0.f;
}

// ---------------- kernel 2: per-row sums + normalized output ---------------
// 16 lanes per row, 2 rows per group, 4 groups/wave, 4 waves/block
// -> 32 rows/block, grid = B/32 = 1024 blocks.
// Speaker sums: per-block LDS aggregation -> 2 atomics/block (fast path),
// per-row fallback if the block spans multiple speakers.
__global__ __launch_bounds__(256) void rows_kernel(
        const float* __restrict__ x, const int* __restrict__ tgt,
        float* __restrict__ outN,
        float* __restrict__ rowsum, float* __restrict__ sqsum,
        float* __restrict__ s, float* __restrict__ cnt) {
    int wave = threadIdx.x >> 6;
    int lane = threadIdx.x & 63;
    int li   = lane & 15;          // lane within 16-group
    int sub  = lane >> 4;          // group within wave
    int rowA = blockIdx.x * 32 + wave * 8 + sub * 2;
    int rowB = rowA + 1;

    const fx4* __restrict__ xa = (const fx4*)(x + (size_t)rowA * E_);
    const fx4* __restrict__ xb = (const fx4*)(x + (size_t)rowB * E_);
    fx4* __restrict__ oa = (fx4*)(outN + (size_t)rowA * E_);
    fx4* __restrict__ ob = (fx4*)(outN + (size_t)rowB * E_);

    // 8 independent loads
    fx4 a0 = xa[li];
    fx4 a1 = xa[li + 16];
    fx4 a2 = xa[li + 32];
    fx4 a3 = xa[li + 48];
    fx4 b0 = xb[li];
    fx4 b1 = xb[li + 16];
    fx4 b2 = xb[li + 32];
    fx4 b3 = xb[li + 48];

    float sumA = (a0.x + a0.y + a0.z + a0.w) + (a1.x + a1.y + a1.z + a1.w)
               + (a2.x + a2.y + a2.z + a2.w) + (a3.x + a3.y + a3.z + a3.w);
    float sqA  = (a0.x*a0.x + a0.y*a0.y + a0.z*a0.z + a0.w*a0.w)
               + (a1.x*a1.x + a1.y*a1.y + a1.z*a1.z + a1.w*a1.w)
               + (a2.x*a2.x + a2.y*a2.y + a2.z*a2.z + a2.w*a2.w)
               + (a3.x*a3.x + a3.y*a3.y + a3.z*a3.z + a3.w*a3.w);
    float sumB = (b0.x + b0.y + b0.z + b0.w) + (b1.x + b1.y + b1.z + b1.w)
               + (b2.x + b2.y + b2.z + b2.w) + (b3.x + b3.y + b3.z + b3.w);
    float sqB  = (b0.x*b0.x + b0.y*b0.y + b0.z*b0.z + b0.w*b0.w)
               + (b1.x*b1.x + b1.y*b1.y + b1.z*b1.z + b1.w*b1.w)
               + (b2.x*b2.x + b2.y*b2.y + b2.z*b2.z + b2.w*b2.w)
               + (b3.x*b3.x + b3.y*b3.y + b3.z*b3.z + b3.w*b3.w);

    // 4 independent butterfly chains interleave (intra-16-lane)
    #pragma unroll
    for (int o = 8; o >= 1; o >>= 1) {
        sumA += __shfl_xor(sumA, o, 64);
        sqA  += __shfl_xor(sqA,  o, 64);
        sumB += __shfl_xor(sumB, o, 64);
        sqB  += __shfl_xor(sqB,  o, 64);
    }

    float rnA = 1.0f / fmaxf(sqrtf(sqA), EPS_NORM);
    float rnB = 1.0f / fmaxf(sqrtf(sqB), EPS_NORM);

    __builtin_nontemporal_store(a0 * rnA, &oa[li]);
    __builtin_nontemporal_store(a1 * rnA, &oa[li + 16]);
    __builtin_nontemporal_store(a2 * rnA, &oa[li + 32]);
    __builtin_nontemporal_store(a3 * rnA, &oa[li + 48]);
    __builtin_nontemporal_store(b0 * rnB, &ob[li]);
    __builtin_nontemporal_store(b1 * rnB, &ob[li + 16]);
    __builtin_nontemporal_store(b2 * rnB, &ob[li + 32]);
    __builtin_nontemporal_store(b3 * rnB, &ob[li + 48]);

    // ---- per-block speaker aggregation (replaces 64 global atomics) ----
    __shared__ float sSum[32];
    __shared__ int   sTgt[32];
    if (li == 0) {
        rowsum[rowA] = sumA;
        sqsum[rowA]  = sqA;
        rowsum[rowB] = sumB;
        sqsum[rowB]  = sqB;
        int slot = wave * 8 + sub * 2;
        sSum[slot]     = sumA;
        sSum[slot + 1] = sumB;
        sTgt[slot]     = tgt[rowA];
        sTgt[slot + 1] = tgt[rowB];
    }
    __syncthreads();
    if (threadIdx.x < 32) {
        float v = sSum[threadIdx.x];
        int   t = sTgt[threadIdx.x];
        int tmn = t, tmx = t;
        float tot = v;
        #pragma unroll
        for (int o = 16; o >= 1; o >>= 1) {
            tot += __shfl_xor(tot, o, 32);
            tmn  = min(tmn, __shfl_xor(tmn, o, 32));
            tmx  = max(tmx, __shfl_xor(tmx, o, 32));
        }
        if (tmn == tmx) {                 // whole block = one speaker
            if (threadIdx.x == 0) {
                atomicAdd(&s[t], tot);
                atomicAdd(&cnt[t], 32.0f);
            }
        } else {                          // rare/general fallback
            atomicAdd(&s[t], v);
            atomicAdd(&cnt[t], 1.0f);
        }
    }
}

// ---------------- kernel 3: fused c-buckets + per-row loss + reduce --------
__global__ __launch_bounds__(256) void loss_kernel(
        const float* __restrict__ rowsum, const float* __restrict__ sqsum,
        const int* __restrict__ tgt,
        const float* __restrict__ s, const float* __restrict__ cnt,
        const float* __restrict__ wP, const float* __restrict__ bP,
        float* __restrict__ outL) {
    // --- per-block recompute of sign-bucket counts over S (L2-hot, 8 KB) ---
    int packed = 0;   // (npos << 16) | nneg
    #pragma unroll
    for (int j = 0; j < S_ / 256; ++j) {
        int k = threadIdx.x * (S_ / 256) + j;
        float cv = s[k] / cnt[k];
        if (fabsf(cv) * 16.0f >= EPS_COS) packed += (cv > 0.f) ? (1 << 16) : 1;
    }
    __shared__ int ired[256];
    ired[threadIdx.x] = packed;
    __syncthreads();
    #pragma unroll
    for (int st = 128; st > 0; st >>= 1) {
        if (threadIdx.x < st) ired[threadIdx.x] += ired[threadIdx.x + st];
        __syncthreads();
    }
    int npos = ired[0] >> 16, nneg = ired[0] & 0xFFFF;

    // --- per-row loss ---
    int i = blockIdx.x * blockDim.x + threadIdx.x;   // grid = B/256 blocks
    float w  = wP[0], b = bP[0];
    float wr = fmaxf(w, 0.f);

    int   t  = tgt[i];
    float rs = rowsum[i], sq = sqsum[i];
    float sj = s[t],      nj = cnt[t];

    float ne  = sqrtf(sq);
    float nem = fmaxf(ne, EPS_COS);

    float dot = (sj * rs - sq) / nj;
    float nc  = sqrtf((float)E_ * sj * sj - 2.f * sj * rs + sq) / nj;
    float self_cos = dot / (nem * fmaxf(nc, EPS_COS));
    float self_sim = wr * self_cos + b;

    float A  = wr * rs / (nem * 16.0f);
    float xp =  A + b, xm = -A + b, xz = b;

    float ct = sj / nj;
    int np = npos, nm = nneg, nz = S_ - npos - nneg;
    if (fabsf(ct) * 16.0f >= EPS_COS) { if (ct > 0.f) np--; else nm--; }
    else nz--;

    float m = self_sim;
    if (np > 0) m = fmaxf(m, xp);
    if (nm > 0) m = fmaxf(m, xm);
    if (nz > 0) m = fmaxf(m, xz);
    float ssum = expf(self_sim - m)
               + (float)np * expf(xp - m)
               + (float)nm * expf(xm - m)
               + (float)nz * expf(xz - m);
    float contrib = m + logf(ssum) - self_sim;

    __shared__ float fred[256];
    fred[threadIdx.x] = contrib;
    __syncthreads();
    #pragma unroll
    for (int st = 128; st > 0; st >>= 1) {
        if (threadIdx.x < st) fred[threadIdx.x] += fred[threadIdx.x + st];
        __syncthreads();
    }
    if (threadIdx.x == 0) atomicAdd(outL, fred[0]);
}

extern "C" void kernel_launch(void* const* d_in, const int* in_sizes, int n_in,
                              void* d_out, int out_size, void* d_ws, size_t ws_size,
                              hipStream_t stream) {
    const float* inputs  = (const float*)d_in[0];
    const int*   targets = (const int*)d_in[1];
    const float* wP      = (const float*)d_in[2];
    const float* bP      = (const float*)d_in[3];
    float* outN = (float*)d_out;                    // [B,E] normalized
    float* outL = (float*)d_out + (size_t)B_ * E_;  // [1] loss

    float* wsf    = (float*)d_ws;
    float* rowsum = wsf;                 // B
    float* sqsum  = wsf + B_;            // B
    float* sArr   = wsf + 2 * B_;        // S
    float* cntArr = sArr + S_;           // S

    zero_ws_kernel<<<S_ / 256, 256, 0, stream>>>(sArr, cntArr, outL);
    rows_kernel<<<B_ / 32, 256, 0, stream>>>(inputs, targets, outN,
                                             rowsum, sqsum, sArr, cntArr);
    loss_kernel<<<B_ / 256, 256, 0, stream>>>(rowsum, sqsum, targets,
                                              sArr, cntArr, wP, bP, outL);
}

// Round 7
// 24.147 us; speedup vs baseline: 2.8273x; 1.0051x over previous
//
#include <hip/hip_runtime.h>
#include <hip/hip_cooperative_groups.h>
#include <math.h>

#define B_ 32768
#define E_ 256
#define S_ 1024
#define EPS_COS 1e-8f
#define EPS_NORM 1e-12f

typedef float fx4 __attribute__((ext_vector_type(4)));

namespace cg = cooperative_groups;

// =================== fused cooperative kernel ==============================
// Grid = B/64 = 512 blocks, 256 threads (4 waves). Block b owns rows
// [64b, 64b+64) = speakers 2b, 2b+1 in the balanced layout.
// __launch_bounds__(256,2): VGPR<=256 -> >=2 blocks/CU -> 512 co-resident.
__global__ __launch_bounds__(256, 2) void fused_kernel(
        const float* __restrict__ x, const int* __restrict__ tgt,
        float* __restrict__ outN, float* __restrict__ outL,
        float* __restrict__ s, float* __restrict__ cnt,
        const float* __restrict__ wP, const float* __restrict__ bP) {
    __shared__ float sSum[64];
    __shared__ float sSq[64];
    __shared__ int   sTgt[64];
    __shared__ int   ired[256];

    int g  = threadIdx.x >> 4;           // 16 groups of 16 lanes
    int li = threadIdx.x & 15;
    int r0 = blockIdx.x * 64 + g * 4;    // this group's first row

    // ---- Phase A: zero own slots via device-scope atomics ----
    if (threadIdx.x < 2) {
        atomicExch(&s[blockIdx.x * 2 + threadIdx.x], 0.f);
        atomicExch(&cnt[blockIdx.x * 2 + threadIdx.x], 0.f);
    }
    if (blockIdx.x == 0 && threadIdx.x == 2) atomicExch(outL, 0.f);

    const fx4* __restrict__ xr = (const fx4*)(x + (size_t)r0 * E_);
    fx4* __restrict__ orow = (fx4*)(outN + (size_t)r0 * E_);

    // 16 independent loads (4 rows x 4 chunks); row stride = 64 fx4
    fx4 a0 = xr[li];       fx4 a1 = xr[li + 16];
    fx4 a2 = xr[li + 32];  fx4 a3 = xr[li + 48];
    fx4 b0 = xr[li + 64];  fx4 b1 = xr[li + 80];
    fx4 b2 = xr[li + 96];  fx4 b3 = xr[li + 112];
    fx4 c0 = xr[li + 128]; fx4 c1 = xr[li + 144];
    fx4 c2 = xr[li + 160]; fx4 c3 = xr[li + 176];
    fx4 d0 = xr[li + 192]; fx4 d1 = xr[li + 208];
    fx4 d2 = xr[li + 224]; fx4 d3 = xr[li + 240];

    float sA = (a0.x+a0.y+a0.z+a0.w)+(a1.x+a1.y+a1.z+a1.w)
             + (a2.x+a2.y+a2.z+a2.w)+(a3.x+a3.y+a3.z+a3.w);
    float qA = (a0.x*a0.x+a0.y*a0.y+a0.z*a0.z+a0.w*a0.w)
             + (a1.x*a1.x+a1.y*a1.y+a1.z*a1.z+a1.w*a1.w)
             + (a2.x*a2.x+a2.y*a2.y+a2.z*a2.z+a2.w*a2.w)
             + (a3.x*a3.x+a3.y*a3.y+a3.z*a3.z+a3.w*a3.w);
    float sB = (b0.x+b0.y+b0.z+b0.w)+(b1.x+b1.y+b1.z+b1.w)
             + (b2.x+b2.y+b2.z+b2.w)+(b3.x+b3.y+b3.z+b3.w);
    float qB = (b0.x*b0.x+b0.y*b0.y+b0.z*b0.z+b0.w*b0.w)
             + (b1.x*b1.x+b1.y*b1.y+b1.z*b1.z+b1.w*b1.w)
             + (b2.x*b2.x+b2.y*b2.y+b2.z*b2.z+b2.w*b2.w)
             + (b3.x*b3.x+b3.y*b3.y+b3.z*b3.z+b3.w*b3.w);
    float sC = (c0.x+c0.y+c0.z+c0.w)+(c1.x+c1.y+c1.z+c1.w)
             + (c2.x+c2.y+c2.z+c2.w)+(c3.x+c3.y+c3.z+c3.w);
    float qC = (c0.x*c0.x+c0.y*c0.y+c0.z*c0.z+c0.w*c0.w)
             + (c1.x*c1.x+c1.y*c1.y+c1.z*c1.z+c1.w*c1.w)
             + (c2.x*c2.x+c2.y*c2.y+c2.z*c2.z+c2.w*c2.w)
             + (c3.x*c3.x+c3.y*c3.y+c3.z*c3.z+c3.w*c3.w);
    float sD = (d0.x+d0.y+d0.z+d0.w)+(d1.x+d1.y+d1.z+d1.w)
             + (d2.x+d2.y+d2.z+d2.w)+(d3.x+d3.y+d3.z+d3.w);
    float qD = (d0.x*d0.x+d0.y*d0.y+d0.z*d0.z+d0.w*d0.w)
             + (d1.x*d1.x+d1.y*d1.y+d1.z*d1.z+d1.w*d1.w)
             + (d2.x*d2.x+d2.y*d2.y+d2.z*d2.z+d2.w*d2.w)
             + (d3.x*d3.x+d3.y*d3.y+d3.z*d3.z+d3.w*d3.w);

    #pragma unroll
    for (int o = 8; o >= 1; o >>= 1) {   // intra-16-lane, 8 chains interleave
        sA += __shfl_xor(sA, o, 64);  qA += __shfl_xor(qA, o, 64);
        sB += __shfl_xor(sB, o, 64);  qB += __shfl_xor(qB, o, 64);
        sC += __shfl_xor(sC, o, 64);  qC += __shfl_xor(qC, o, 64);
        sD += __shfl_xor(sD, o, 64);  qD += __shfl_xor(qD, o, 64);
    }

    float rA = 1.0f / fmaxf(sqrtf(qA), EPS_NORM);
    float rB = 1.0f / fmaxf(sqrtf(qB), EPS_NORM);
    float rC = 1.0f / fmaxf(sqrtf(qC), EPS_NORM);
    float rD = 1.0f / fmaxf(sqrtf(qD), EPS_NORM);

    __builtin_nontemporal_store(a0 * rA, &orow[li]);
    __builtin_nontemporal_store(a1 * rA, &orow[li + 16]);
    __builtin_nontemporal_store(a2 * rA, &orow[li + 32]);
    __builtin_nontemporal_store(a3 * rA, &orow[li + 48]);
    __builtin_nontemporal_store(b0 * rB, &orow[li + 64]);
    __builtin_nontemporal_store(b1 * rB, &orow[li + 80]);
    __builtin_nontemporal_store(b2 * rB, &orow[li + 96]);
    __builtin_nontemporal_store(b3 * rB, &orow[li + 112]);
    __builtin_nontemporal_store(c0 * rC, &orow[li + 128]);
    __builtin_nontemporal_store(c1 * rC, &orow[li + 144]);
    __builtin_nontemporal_store(c2 * rC, &orow[li + 160]);
    __builtin_nontemporal_store(c3 * rC, &orow[li + 176]);
    __builtin_nontemporal_store(d0 * rD, &orow[li + 192]);
    __builtin_nontemporal_store(d1 * rD, &orow[li + 208]);
    __builtin_nontemporal_store(d2 * rD, &orow[li + 224]);
    __builtin_nontemporal_store(d3 * rD, &orow[li + 240]);

    if (li == 0) {
        int slot = g * 4;
        sSum[slot]   = sA; sSq[slot]   = qA; sTgt[slot]   = tgt[r0];
        sSum[slot+1] = sB; sSq[slot+1] = qB; sTgt[slot+1] = tgt[r0+1];
        sSum[slot+2] = sC; sSq[slot+2] = qC; sTgt[slot+2] = tgt[r0+2];
        sSum[slot+3] = sD; sSq[slot+3] = qD; sTgt[slot+3] = tgt[r0+3];
    }
    __syncthreads();

    cg::grid_group grid = cg::this_grid();
    grid.sync();                                   // sync1: zeroing visible

    // ---- Phase B: speaker accumulation (two 32-row halves) ----
    if (threadIdx.x < 64) {                        // wave 0, width-32 halves
        float v = sSum[threadIdx.x];
        int   t = sTgt[threadIdx.x];
        int tmn = t, tmx = t;
        float tot = v;
        #pragma unroll
        for (int o = 16; o >= 1; o >>= 1) {
            tot += __shfl_xor(tot, o, 32);
            tmn  = min(tmn, __shfl_xor(tmn, o, 32));
            tmx  = max(tmx, __shfl_xor(tmx, o, 32));
        }
        if (tmn == tmx) {                 // half = one speaker
            if ((threadIdx.x & 31) == 0) {
                atomicAdd(&s[t], tot);
                atomicAdd(&cnt[t], 32.0f);
            }
        } else {                          // general fallback
            atomicAdd(&s[t], v);
            atomicAdd(&cnt[t], 1.0f);
        }
    }
    grid.sync();                                   // sync2: s/cnt complete

    // ---- Phase C: sign buckets (L2-hot scan) + per-row loss ----
    int packed = 0;   // (npos << 16) | nneg
    #pragma unroll
    for (int j = 0; j < S_ / 256; ++j) {
        int k = threadIdx.x * (S_ / 256) + j;
        float cv = s[k] / cnt[k];
        if (fabsf(cv) * 16.0f >= EPS_COS) packed += (cv > 0.f) ? (1 << 16) : 1;
    }
    ired[threadIdx.x] = packed;
    __syncthreads();
    #pragma unroll
    for (int st = 128; st > 0; st >>= 1) {
        if (threadIdx.x < st) ired[threadIdx.x] += ired[threadIdx.x + st];
        __syncthreads();
    }
    int npos = ired[0] >> 16, nneg = ired[0] & 0xFFFF;

    if (threadIdx.x < 64) {
        float w  = wP[0], b = bP[0];
        float wr = fmaxf(w, 0.f);

        int   t  = sTgt[threadIdx.x];
        float rs = sSum[threadIdx.x], sq = sSq[threadIdx.x];
        float sj = s[t],              nj = cnt[t];

        float nem = fmaxf(sqrtf(sq), EPS_COS);

        float dot = (sj * rs - sq) / nj;
        float nc  = sqrtf((float)E_ * sj * sj - 2.f * sj * rs + sq) / nj;
        float self_cos = dot / (nem * fmaxf(nc, EPS_COS));
        float self_sim = wr * self_cos + b;

        float A  = wr * rs / (nem * 16.0f);
        float xp =  A + b, xm = -A + b, xz = b;

        float ct = sj / nj;
        int np = npos, nm = nneg, nz = S_ - npos - nneg;
        if (fabsf(ct) * 16.0f >= EPS_COS) { if (ct > 0.f) np--; else nm--; }
        else nz--;

        float m = self_sim;
        if (np > 0) m = fmaxf(m, xp);
        if (nm > 0) m = fmaxf(m, xm);
        if (nz > 0) m = fmaxf(m, xz);
        float ssum = expf(self_sim - m)
                   + (float)np * expf(xp - m)
                   + (float)nm * expf(xm - m)
                   + (float)nz * expf(xz - m);
        float contrib = m + logf(ssum) - self_sim;

        #pragma unroll
        for (int o = 32; o >= 1; o >>= 1)
            contrib += __shfl_xor(contrib, o, 64);
        if (threadIdx.x == 0) atomicAdd(outL, contrib);
    }
}

// =================== fallback path (proven R5 kernels) =====================
__global__ void zero_ws_kernel(float* s, float* cnt, float* outL) {
    int i = blockIdx.x * blockDim.x + threadIdx.x;
    if (i < S_) { s[i] = 0.f; cnt[i] = 0.f; }
    if (i == 0) outL[0] = 0.f;
}

__global__ __launch_bounds__(256) void rows_kernel(
        const float* __restrict__ x, const int* __restrict__ tgt,
        float* __restrict__ outN,
        float* __restrict__ rowsum, float* __restrict__ sqsum,
        float* __restrict__ s, float* __restrict__ cnt) {
    int wave = threadIdx.x >> 6;
    int lane = threadIdx.x & 63;
    int li   = lane & 15;
    int sub  = lane >> 4;
    int rowA = blockIdx.x * 32 + wave * 8 + sub * 2;
    int rowB = rowA + 1;

    const fx4* __restrict__ xa = (const fx4*)(x + (size_t)rowA * E_);
    const fx4* __restrict__ xb = (const fx4*)(x + (size_t)rowB * E_);
    fx4* __restrict__ oa = (fx4*)(outN + (size_t)rowA * E_);
    fx4* __restrict__ ob = (fx4*)(outN + (size_t)rowB * E_);

    fx4 a0 = xa[li]; fx4 a1 = xa[li + 16]; fx4 a2 = xa[li + 32]; fx4 a3 = xa[li + 48];
    fx4 b0 = xb[li]; fx4 b1 = xb[li + 16]; fx4 b2 = xb[li + 32]; fx4 b3 = xb[li + 48];

    float sumA = (a0.x+a0.y+a0.z+a0.w)+(a1.x+a1.y+a1.z+a1.w)
               + (a2.x+a2.y+a2.z+a2.w)+(a3.x+a3.y+a3.z+a3.w);
    float sqA  = (a0.x*a0.x+a0.y*a0.y+a0.z*a0.z+a0.w*a0.w)
               + (a1.x*a1.x+a1.y*a1.y+a1.z*a1.z+a1.w*a1.w)
               + (a2.x*a2.x+a2.y*a2.y+a2.z*a2.z+a2.w*a2.w)
               + (a3.x*a3.x+a3.y*a3.y+a3.z*a3.z+a3.w*a3.w);
    float sumB = (b0.x+b0.y+b0.z+b0.w)+(b1.x+b1.y+b1.z+b1.w)
               + (b2.x+b2.y+b2.z+b2.w)+(b3.x+b3.y+b3.z+b3.w);
    float sqB  = (b0.x*b0.x+b0.y*b0.y+b0.z*b0.z+b0.w*b0.w)
               + (b1.x*b1.x+b1.y*b1.y+b1.z*b1.z+b1.w*b1.w)
               + (b2.x*b2.x+b2.y*b2.y+b2.z*b2.z+b2.w*b2.w)
               + (b3.x*b3.x+b3.y*b3.y+b3.z*b3.z+b3.w*b3.w);

    #pragma unroll
    for (int o = 8; o >= 1; o >>= 1) {
        sumA += __shfl_xor(sumA, o, 64); sqA += __shfl_xor(sqA, o, 64);
        sumB += __shfl_xor(sumB, o, 64); sqB += __shfl_xor(sqB, o, 64);
    }

    float rnA = 1.0f / fmaxf(sqrtf(sqA), EPS_NORM);
    float rnB = 1.0f / fmaxf(sqrtf(sqB), EPS_NORM);

    __builtin_nontemporal_store(a0 * rnA, &oa[li]);
    __builtin_nontemporal_store(a1 * rnA, &oa[li + 16]);
    __builtin_nontemporal_store(a2 * rnA, &oa[li + 32]);
    __builtin_nontemporal_store(a3 * rnA, &oa[li + 48]);
    __builtin_nontemporal_store(b0 * rnB, &ob[li]);
    __builtin_nontemporal_store(b1 * rnB, &ob[li + 16]);
    __builtin_nontemporal_store(b2 * rnB, &ob[li + 32]);
    __builtin_nontemporal_store(b3 * rnB, &ob[li + 48]);

    __shared__ float sSum[32];
    __shared__ int   sTgt[32];
    if (li == 0) {
        rowsum[rowA] = sumA; sqsum[rowA] = sqA;
        rowsum[rowB] = sumB; sqsum[rowB] = sqB;
        int slot = wave * 8 + sub * 2;
        sSum[slot] = sumA; sSum[slot + 1] = sumB;
        sTgt[slot] = tgt[rowA]; sTgt[slot + 1] = tgt[rowB];
    }
    __syncthreads();
    if (threadIdx.x < 32) {
        float v = sSum[threadIdx.x];
        int   t = sTgt[threadIdx.x];
        int tmn = t, tmx = t;
        float tot = v;
        #pragma unroll
        for (int o = 16; o >= 1; o >>= 1) {
            tot += __shfl_xor(tot, o, 32);
            tmn  = min(tmn, __shfl_xor(tmn, o, 32));
            tmx  = max(tmx, __shfl_xor(tmx, o, 32));
        }
        if (tmn == tmx) {
            if (threadIdx.x == 0) { atomicAdd(&s[t], tot); atomicAdd(&cnt[t], 32.0f); }
        } else {
            atomicAdd(&s[t], v); atomicAdd(&cnt[t], 1.0f);
        }
    }
}

__global__ __launch_bounds__(256) void loss_kernel(
        const float* __restrict__ rowsum, const float* __restrict__ sqsum,
        const int* __restrict__ tgt,
        const float* __restrict__ s, const float* __restrict__ cnt,
        const float* __restrict__ wP, const float* __restrict__ bP,
        float* __restrict__ outL) {
    int packed = 0;
    #pragma unroll
    for (int j = 0; j < S_ / 256; ++j) {
        int k = threadIdx.x * (S_ / 256) + j;
        float cv = s[k] / cnt[k];
        if (fabsf(cv) * 16.0f >= EPS_COS) packed += (cv > 0.f) ? (1 << 16) : 1;
    }
    __shared__ int ired[256];
    ired[threadIdx.x] = packed;
    __syncthreads();
    #pragma unroll
    for (int st = 128; st > 0; st >>= 1) {
        if (threadIdx.x < st) ired[threadIdx.x] += ired[threadIdx.x + st];
        __syncthreads();
    }
    int npos = ired[0] >> 16, nneg = ired[0] & 0xFFFF;

    int i = blockIdx.x * blockDim.x + threadIdx.x;
    float w  = wP[0], b = bP[0];
    float wr = fmaxf(w, 0.f);

    int   t  = tgt[i];
    float rs = rowsum[i], sq = sqsum[i];
    float sj = s[t],      nj = cnt[t];

    float nem = fmaxf(sqrtf(sq), EPS_COS);
    float dot = (sj * rs - sq) / nj;
    float nc  = sqrtf((float)E_ * sj * sj - 2.f * sj * rs + sq) / nj;
    float self_cos = dot / (nem * fmaxf(nc, EPS_COS));
    float self_sim = wr * self_cos + b;

    float A  = wr * rs / (nem * 16.0f);
    float xp =  A + b, xm = -A + b, xz = b;

    float ct = sj / nj;
    int np = npos, nm = nneg, nz = S_ - npos - nneg;
    if (fabsf(ct) * 16.0f >= EPS_COS) { if (ct > 0.f) np--; else nm--; }
    else nz--;

    float m = self_sim;
    if (np > 0) m = fmaxf(m, xp);
    if (nm > 0) m = fmaxf(m, xm);
    if (nz > 0) m = fmaxf(m, xz);
    float ssum = expf(self_sim - m)
               + (float)np * expf(xp - m)
               + (float)nm * expf(xm - m)
               + (float)nz * expf(xz - m);
    float contrib = m + logf(ssum) - self_sim;

    __shared__ float fred[256];
    fred[threadIdx.x] = contrib;
    __syncthreads();
    #pragma unroll
    for (int st = 128; st > 0; st >>= 1) {
        if (threadIdx.x < st) fred[threadIdx.x] += fred[threadIdx.x + st];
        __syncthreads();
    }
    if (threadIdx.x == 0) atomicAdd(outL, fred[0]);
}

extern "C" void kernel_launch(void* const* d_in, const int* in_sizes, int n_in,
                              void* d_out, int out_size, void* d_ws, size_t ws_size,
                              hipStream_t stream) {
    const float* inputs  = (const float*)d_in[0];
    const int*   targets = (const int*)d_in[1];
    const float* wP      = (const float*)d_in[2];
    const float* bP      = (const float*)d_in[3];
    float* outN = (float*)d_out;                    // [B,E] normalized
    float* outL = (float*)d_out + (size_t)B_ * E_;  // [1] loss

    float* wsf    = (float*)d_ws;
    float* rowsum = wsf;                 // B
    float* sqsum  = wsf + B_;            // B
    float* sArr   = wsf + 2 * B_;        // S
    float* cntArr = sArr + S_;           // S

    int nb = 0;
    hipOccupancyMaxActiveBlocksPerMultiprocessor(&nb, fused_kernel, 256, 0);

    if (nb >= 2) {   // 512 blocks co-resident on 256 CUs -> cooperative OK
        void* args[] = { (void*)&inputs, (void*)&targets, (void*)&outN,
                         (void*)&outL, (void*)&sArr, (void*)&cntArr,
                         (void*)&wP, (void*)&bP };
        hipLaunchCooperativeKernel((void*)fused_kernel, dim3(B_ / 64),
                                   dim3(256), args, 0, stream);
    } else {         // deterministic fallback: proven 3-kernel path
        zero_ws_kernel<<<S_ / 256, 256, 0, stream>>>(sArr, cntArr, outL);
        rows_kernel<<<B_ / 32, 256, 0, stream>>>(inputs, targets, outN,
                                                 rowsum, sqsum, sArr, cntArr);
        loss_kernel<<<B_ / 256, 256, 0, stream>>>(rowsum, sqsum, targets,
                                                  sArr, cntArr, wP, bP, outL);
    }
}

// Round 8
// 23.968 us; speedup vs baseline: 2.8484x; 1.0075x over previous
//
#include <hip/hip_runtime.h>
#include <hip/hip_cooperative_groups.h>
#include <math.h>

#define B_ 32768
#define E_ 256
#define S_ 1024
#define EPS_COS 1e-8f
#define EPS_NORM 1e-12f

typedef float fx4 __attribute__((ext_vector_type(4)));

namespace cg = cooperative_groups;

// =================== fused cooperative kernel (v2) =========================
// Grid = 512 blocks x 512 threads (8 waves): 2 blocks/CU -> 16 waves/CU.
// Block b owns rows [64b, 64b+64). 16-lane group g handles rows 64b+2g(+1).
// Phase A: row sums + normalized stores; per-32-row-half partials to PB
//          (non-atomic, own slots -> no zeroing, no global atomics).
// ONE grid.sync.
// Phase C: all blocks read all 1024 PB partials -> full speaker histogram
//          in LDS -> sign buckets + 64 per-row losses -> 1 atomicAdd(outL).
__global__ __launch_bounds__(512, 2) void fused_kernel(
        const float* __restrict__ x, const int* __restrict__ tgt,
        float* __restrict__ outN, float* __restrict__ outL,
        float* __restrict__ PBsum, int* __restrict__ PBtgt,
        float* __restrict__ rowsum,
        const float* __restrict__ wP, const float* __restrict__ bP) {
    __shared__ float sSum[64];
    __shared__ float sSq[64];
    __shared__ int   sTgt[64];
    __shared__ float s_h[S_];
    __shared__ float c_h[S_];
    __shared__ int   ired[512];

    int tid = threadIdx.x;
    int g   = tid >> 4;                  // 32 groups of 16 lanes
    int li  = tid & 15;
    int r0  = blockIdx.x * 64 + g * 2;
    int r1  = r0 + 1;

    if (blockIdx.x == 0 && tid == 0) atomicExch(outL, 0.f);

    const fx4* __restrict__ xa = (const fx4*)(x + (size_t)r0 * E_);
    const fx4* __restrict__ xb = (const fx4*)(x + (size_t)r1 * E_);
    fx4* __restrict__ oa = (fx4*)(outN + (size_t)r0 * E_);
    fx4* __restrict__ ob = (fx4*)(outN + (size_t)r1 * E_);

    // 8 independent loads
    fx4 a0 = xa[li];       fx4 a1 = xa[li + 16];
    fx4 a2 = xa[li + 32];  fx4 a3 = xa[li + 48];
    fx4 b0 = xb[li];       fx4 b1 = xb[li + 16];
    fx4 b2 = xb[li + 32];  fx4 b3 = xb[li + 48];

    float sumA = (a0.x+a0.y+a0.z+a0.w)+(a1.x+a1.y+a1.z+a1.w)
               + (a2.x+a2.y+a2.z+a2.w)+(a3.x+a3.y+a3.z+a3.w);
    float sqA  = (a0.x*a0.x+a0.y*a0.y+a0.z*a0.z+a0.w*a0.w)
               + (a1.x*a1.x+a1.y*a1.y+a1.z*a1.z+a1.w*a1.w)
               + (a2.x*a2.x+a2.y*a2.y+a2.z*a2.z+a2.w*a2.w)
               + (a3.x*a3.x+a3.y*a3.y+a3.z*a3.z+a3.w*a3.w);
    float sumB = (b0.x+b0.y+b0.z+b0.w)+(b1.x+b1.y+b1.z+b1.w)
               + (b2.x+b2.y+b2.z+b2.w)+(b3.x+b3.y+b3.z+b3.w);
    float sqB  = (b0.x*b0.x+b0.y*b0.y+b0.z*b0.z+b0.w*b0.w)
               + (b1.x*b1.x+b1.y*b1.y+b1.z*b1.z+b1.w*b1.w)
               + (b2.x*b2.x+b2.y*b2.y+b2.z*b2.z+b2.w*b2.w)
               + (b3.x*b3.x+b3.y*b3.y+b3.z*b3.z+b3.w*b3.w);

    #pragma unroll
    for (int o = 8; o >= 1; o >>= 1) {   // intra-16-lane, 4 chains interleave
        sumA += __shfl_xor(sumA, o, 64);  sqA += __shfl_xor(sqA, o, 64);
        sumB += __shfl_xor(sumB, o, 64);  sqB += __shfl_xor(sqB, o, 64);
    }

    float rnA = 1.0f / fmaxf(sqrtf(sqA), EPS_NORM);
    float rnB = 1.0f / fmaxf(sqrtf(sqB), EPS_NORM);

    __builtin_nontemporal_store(a0 * rnA, &oa[li]);
    __builtin_nontemporal_store(a1 * rnA, &oa[li + 16]);
    __builtin_nontemporal_store(a2 * rnA, &oa[li + 32]);
    __builtin_nontemporal_store(a3 * rnA, &oa[li + 48]);
    __builtin_nontemporal_store(b0 * rnB, &ob[li]);
    __builtin_nontemporal_store(b1 * rnB, &ob[li + 16]);
    __builtin_nontemporal_store(b2 * rnB, &ob[li + 32]);
    __builtin_nontemporal_store(b3 * rnB, &ob[li + 48]);

    if (li == 0) {
        rowsum[r0] = sumA;               // for general fallback only
        rowsum[r1] = sumB;
        sSum[2*g]   = sumA; sSq[2*g]   = sqA; sTgt[2*g]   = tgt[r0];
        sSum[2*g+1] = sumB; sSq[2*g+1] = sqB; sTgt[2*g+1] = tgt[r1];
    }
    __syncthreads();

    // per-32-row-half aggregation by wave 0 -> PB (own slots, non-atomic)
    if (tid < 64) {
        float v = sSum[tid];
        int   t = sTgt[tid];
        int tmn = t, tmx = t;
        float tot = v;
        #pragma unroll
        for (int o = 16; o >= 1; o >>= 1) {
            tot += __shfl_xor(tot, o, 32);
            tmn  = min(tmn, __shfl_xor(tmn, o, 32));
            tmx  = max(tmx, __shfl_xor(tmx, o, 32));
        }
        if ((tid & 31) == 0) {
            int h = tid >> 5;
            PBsum[blockIdx.x * 2 + h] = tot;
            PBtgt[blockIdx.x * 2 + h] = (tmn == tmx) ? tmn : -1;
        }
    }

    cg::grid_group grid = cg::this_grid();
    grid.sync();                         // the ONLY grid-wide sync

    // ---- Phase C ----
    // zero LDS histogram
    s_h[tid] = 0.f; s_h[tid + 512] = 0.f;
    c_h[tid] = 0.f; c_h[tid + 512] = 0.f;
    // read PB flags (2 per thread), consensus on fast path
    int f0 = PBtgt[2 * tid];
    int f1 = PBtgt[2 * tid + 1];
    float p0 = PBsum[2 * tid];
    float p1 = PBsum[2 * tid + 1];
    ired[tid] = ((f0 | f1) < 0) ? 1 : 0;
    __syncthreads();
    #pragma unroll
    for (int st = 256; st > 0; st >>= 1) {
        if (tid < st) ired[tid] |= ired[tid + st];
        __syncthreads();
    }
    bool slow = (ired[0] != 0);

    if (!slow) {                         // balanced/clustered: 2 LDS adds/thr
        atomicAdd(&s_h[f0], p0);  atomicAdd(&c_h[f0], 32.0f);
        atomicAdd(&s_h[f1], p1);  atomicAdd(&c_h[f1], 32.0f);
    } else {                             // general: full segment-sum (slow, correct)
        for (int i = tid; i < B_; i += 512) {
            int t = tgt[i];
            atomicAdd(&s_h[t], rowsum[i]);
            atomicAdd(&c_h[t], 1.0f);
        }
    }
    __syncthreads();

    // sign buckets over all S speakers (LDS-resident)
    int packed = 0;   // (npos << 16) | nneg
    {
        float cv0 = s_h[tid] / c_h[tid];
        float cv1 = s_h[tid + 512] / c_h[tid + 512];
        if (fabsf(cv0) * 16.0f >= EPS_COS) packed += (cv0 > 0.f) ? (1 << 16) : 1;
        if (fabsf(cv1) * 16.0f >= EPS_COS) packed += (cv1 > 0.f) ? (1 << 16) : 1;
    }
    ired[tid] = packed;
    __syncthreads();
    #pragma unroll
    for (int st = 256; st > 0; st >>= 1) {
        if (tid < st) ired[tid] += ired[tid + st];
        __syncthreads();
    }
    int npos = ired[0] >> 16, nneg = ired[0] & 0xFFFF;

    // per-row loss for the block's 64 rows (wave 0)
    if (tid < 64) {
        float w  = wP[0], b = bP[0];
        float wr = fmaxf(w, 0.f);

        int   t  = sTgt[tid];
        float rs = sSum[tid], sq = sSq[tid];
        float sj = s_h[t],    nj = c_h[t];

        float nem = fmaxf(sqrtf(sq), EPS_COS);

        float dot = (sj * rs - sq) / nj;
        float nc  = sqrtf((float)E_ * sj * sj - 2.f * sj * rs + sq) / nj;
        float self_cos = dot / (nem * fmaxf(nc, EPS_COS));
        float self_sim = wr * self_cos + b;

        float A  = wr * rs / (nem * 16.0f);
        float xp =  A + b, xm = -A + b, xz = b;

        float ct = sj / nj;
        int np = npos, nm = nneg, nz = S_ - npos - nneg;
        if (fabsf(ct) * 16.0f >= EPS_COS) { if (ct > 0.f) np--; else nm--; }
        else nz--;

        float m = self_sim;
        if (np > 0) m = fmaxf(m, xp);
        if (nm > 0) m = fmaxf(m, xm);
        if (nz > 0) m = fmaxf(m, xz);
        float ssum = expf(self_sim - m)
                   + (float)np * expf(xp - m)
                   + (float)nm * expf(xm - m)
                   + (float)nz * expf(xz - m);
        float contrib = m + logf(ssum) - self_sim;

        #pragma unroll
        for (int o = 32; o >= 1; o >>= 1)
            contrib += __shfl_xor(contrib, o, 64);
        if (tid == 0) atomicAdd(outL, contrib);
    }
}

// =================== fallback path (proven R5 kernels) =====================
__global__ void zero_ws_kernel(float* s, float* cnt, float* outL) {
    int i = blockIdx.x * blockDim.x + threadIdx.x;
    if (i < S_) { s[i] = 0.f; cnt[i] = 0.f; }
    if (i == 0) outL[0] = 0.f;
}

__global__ __launch_bounds__(256) void rows_kernel(
        const float* __restrict__ x, const int* __restrict__ tgt,
        float* __restrict__ outN,
        float* __restrict__ rowsum, float* __restrict__ sqsum,
        float* __restrict__ s, float* __restrict__ cnt) {
    int wave = threadIdx.x >> 6;
    int lane = threadIdx.x & 63;
    int li   = lane & 15;
    int sub  = lane >> 4;
    int rowA = blockIdx.x * 32 + wave * 8 + sub * 2;
    int rowB = rowA + 1;

    const fx4* __restrict__ xa = (const fx4*)(x + (size_t)rowA * E_);
    const fx4* __restrict__ xb = (const fx4*)(x + (size_t)rowB * E_);
    fx4* __restrict__ oa = (fx4*)(outN + (size_t)rowA * E_);
    fx4* __restrict__ ob = (fx4*)(outN + (size_t)rowB * E_);

    fx4 a0 = xa[li]; fx4 a1 = xa[li + 16]; fx4 a2 = xa[li + 32]; fx4 a3 = xa[li + 48];
    fx4 b0 = xb[li]; fx4 b1 = xb[li + 16]; fx4 b2 = xb[li + 32]; fx4 b3 = xb[li + 48];

    float sumA = (a0.x+a0.y+a0.z+a0.w)+(a1.x+a1.y+a1.z+a1.w)
               + (a2.x+a2.y+a2.z+a2.w)+(a3.x+a3.y+a3.z+a3.w);
    float sqA  = (a0.x*a0.x+a0.y*a0.y+a0.z*a0.z+a0.w*a0.w)
               + (a1.x*a1.x+a1.y*a1.y+a1.z*a1.z+a1.w*a1.w)
               + (a2.x*a2.x+a2.y*a2.y+a2.z*a2.z+a2.w*a2.w)
               + (a3.x*a3.x+a3.y*a3.y+a3.z*a3.z+a3.w*a3.w);
    float sumB = (b0.x+b0.y+b0.z+b0.w)+(b1.x+b1.y+b1.z+b1.w)
               + (b2.x+b2.y+b2.z+b2.w)+(b3.x+b3.y+b3.z+b3.w);
    float sqB  = (b0.x*b0.x+b0.y*b0.y+b0.z*b0.z+b0.w*b0.w)
               + (b1.x*b1.x+b1.y*b1.y+b1.z*b1.z+b1.w*b1.w)
               + (b2.x*b2.x+b2.y*b2.y+b2.z*b2.z+b2.w*b2.w)
               + (b3.x*b3.x+b3.y*b3.y+b3.z*b3.z+b3.w*b3.w);

    #pragma unroll
    for (int o = 8; o >= 1; o >>= 1) {
        sumA += __shfl_xor(sumA, o, 64); sqA += __shfl_xor(sqA, o, 64);
        sumB += __shfl_xor(sumB, o, 64); sqB += __shfl_xor(sqB, o, 64);
    }

    float rnA = 1.0f / fmaxf(sqrtf(sqA), EPS_NORM);
    float rnB = 1.0f / fmaxf(sqrtf(sqB), EPS_NORM);

    __builtin_nontemporal_store(a0 * rnA, &oa[li]);
    __builtin_nontemporal_store(a1 * rnA, &oa[li + 16]);
    __builtin_nontemporal_store(a2 * rnA, &oa[li + 32]);
    __builtin_nontemporal_store(a3 * rnA, &oa[li + 48]);
    __builtin_nontemporal_store(b0 * rnB, &ob[li]);
    __builtin_nontemporal_store(b1 * rnB, &ob[li + 16]);
    __builtin_nontemporal_store(b2 * rnB, &ob[li + 32]);
    __builtin_nontemporal_store(b3 * rnB, &ob[li + 48]);

    __shared__ float sSum[32];
    __shared__ int   sTgt[32];
    if (li == 0) {
        rowsum[rowA] = sumA; sqsum[rowA] = sqA;
        rowsum[rowB] = sumB; sqsum[rowB] = sqB;
        int slot = wave * 8 + sub * 2;
        sSum[slot] = sumA; sSum[slot + 1] = sumB;
        sTgt[slot] = tgt[rowA]; sTgt[slot + 1] = tgt[rowB];
    }
    __syncthreads();
    if (threadIdx.x < 32) {
        float v = sSum[threadIdx.x];
        int   t = sTgt[threadIdx.x];
        int tmn = t, tmx = t;
        float tot = v;
        #pragma unroll
        for (int o = 16; o >= 1; o >>= 1) {
            tot += __shfl_xor(tot, o, 32);
            tmn  = min(tmn, __shfl_xor(tmn, o, 32));
            tmx  = max(tmx, __shfl_xor(tmx, o, 32));
        }
        if (tmn == tmx) {
            if (threadIdx.x == 0) { atomicAdd(&s[t], tot); atomicAdd(&cnt[t], 32.0f); }
        } else {
            atomicAdd(&s[t], v); atomicAdd(&cnt[t], 1.0f);
        }
    }
}

__global__ __launch_bounds__(256) void loss_kernel(
        const float* __restrict__ rowsum, const float* __restrict__ sqsum,
        const int* __restrict__ tgt,
        const float* __restrict__ s, const float* __restrict__ cnt,
        const float* __restrict__ wP, const float* __restrict__ bP,
        float* __restrict__ outL) {
    int packed = 0;
    #pragma unroll
    for (int j = 0; j < S_ / 256; ++j) {
        int k = threadIdx.x * (S_ / 256) + j;
        float cv = s[k] / cnt[k];
        if (fabsf(cv) * 16.0f >= EPS_COS) packed += (cv > 0.f) ? (1 << 16) : 1;
    }
    __shared__ int ired[256];
    ired[threadIdx.x] = packed;
    __syncthreads();
    #pragma unroll
    for (int st = 128; st > 0; st >>= 1) {
        if (threadIdx.x < st) ired[threadIdx.x] += ired[threadIdx.x + st];
        __syncthreads();
    }
    int npos = ired[0] >> 16, nneg = ired[0] & 0xFFFF;

    int i = blockIdx.x * blockDim.x + threadIdx.x;
    float w  = wP[0], b = bP[0];
    float wr = fmaxf(w, 0.f);

    int   t  = tgt[i];
    float rs = rowsum[i], sq = sqsum[i];
    float sj = s[t],      nj = cnt[t];

    float nem = fmaxf(sqrtf(sq), EPS_COS);
    float dot = (sj * rs - sq) / nj;
    float nc  = sqrtf((float)E_ * sj * sj - 2.f * sj * rs + sq) / nj;
    float self_cos = dot / (nem * fmaxf(nc, EPS_COS));
    float self_sim = wr * self_cos + b;

    float A  = wr * rs / (nem * 16.0f);
    float xp =  A + b, xm = -A + b, xz = b;

    float ct = sj / nj;
    int np = npos, nm = nneg, nz = S_ - npos - nneg;
    if (fabsf(ct) * 16.0f >= EPS_COS) { if (ct > 0.f) np--; else nm--; }
    else nz--;

    float m = self_sim;
    if (np > 0) m = fmaxf(m, xp);
    if (nm > 0) m = fmaxf(m, xm);
    if (nz > 0) m = fmaxf(m, xz);
    float ssum = expf(self_sim - m)
               + (float)np * expf(xp - m)
               + (float)nm * expf(xm - m)
               + (float)nz * expf(xz - m);
    float contrib = m + logf(ssum) - self_sim;

    __shared__ float fred[256];
    fred[threadIdx.x] = contrib;
    __syncthreads();
    #pragma unroll
    for (int st = 128; st > 0; st >>= 1) {
        if (threadIdx.x < st) fred[threadIdx.x] += fred[threadIdx.x + st];
        __syncthreads();
    }
    if (threadIdx.x == 0) atomicAdd(outL, fred[0]);
}

extern "C" void kernel_launch(void* const* d_in, const int* in_sizes, int n_in,
                              void* d_out, int out_size, void* d_ws, size_t ws_size,
                              hipStream_t stream) {
    const float* inputs  = (const float*)d_in[0];
    const int*   targets = (const int*)d_in[1];
    const float* wP      = (const float*)d_in[2];
    const float* bP      = (const float*)d_in[3];
    float* outN = (float*)d_out;                    // [B,E] normalized
    float* outL = (float*)d_out + (size_t)B_ * E_;  // [1] loss

    float* wsf    = (float*)d_ws;
    float* rowsum = wsf;                 // B
    float* sqsum  = wsf + B_;            // B (fallback path only)
    float* sArr   = wsf + 2 * B_;        // S (fallback path only)
    float* cntArr = sArr + S_;           // S (fallback path only)
    float* PBsum  = cntArr + S_;         // 1024
    int*   PBtgt  = (int*)(PBsum + 1024);// 1024

    int nb = 0;
    hipOccupancyMaxActiveBlocksPerMultiprocessor(&nb, fused_kernel, 512, 0);

    if (nb >= 2) {   // 512 blocks co-resident on 256 CUs -> cooperative OK
        void* args[] = { (void*)&inputs, (void*)&targets, (void*)&outN,
                         (void*)&outL, (void*)&PBsum, (void*)&PBtgt,
                         (void*)&rowsum, (void*)&wP, (void*)&bP };
        hipLaunchCooperativeKernel((void*)fused_kernel, dim3(512),
                                   dim3(512), args, 0, stream);
    } else {         // deterministic fallback: proven 3-kernel path
        zero_ws_kernel<<<S_ / 256, 256, 0, stream>>>(sArr, cntArr, outL);
        rows_kernel<<<B_ / 32, 256, 0, stream>>>(inputs, targets, outN,
                                                 rowsum, sqsum, sArr, cntArr);
        loss_kernel<<<B_ / 256, 256, 0, stream>>>(rowsum, sqsum, targets,
                                                  sArr, cntArr, wP, bP, outL);
    }
}